// Round 15
// baseline (73.244 us; speedup 1.0000x reference)
//
#include <hip/hip_runtime.h>
#include <hip/hip_bf16.h>
#include <math.h>

namespace {
constexpr int kC  = 256;   // channels
constexpr int kW  = 48;    // width
constexpr int kM  = 2304;  // tokens = 48*48
constexpr int kB  = 2;     // batch
constexpr int kDH = 32;    // head dim
constexpr int kH  = 8;     // heads
constexpr int kNT = kM / 32;  // 72 tiles of 32 tokens
}

typedef float  f32x4   __attribute__((ext_vector_type(4)));
typedef float  f32x16  __attribute__((ext_vector_type(16)));
typedef __bf16 bf16x8  __attribute__((ext_vector_type(8)));

// 16x16x32: A row=lane&15 ; B col=lane&15 ; D col=lane&15, row=(lane>>4)*4+reg
__device__ __forceinline__ f32x4 mfma16(bf16x8 a, bf16x8 b, f32x4 c) {
    return __builtin_amdgcn_mfma_f32_16x16x32_bf16(a, b, c, 0, 0, 0);
}
// 32x32x16: A row=lane&31 ; B col=lane&31 ; D col=lane&31, row=(reg&3)+8*(reg>>2)+4*(lane>>5)
__device__ __forceinline__ f32x16 mfma32(bf16x8 a, bf16x8 b, f32x16 c) {
    return __builtin_amdgcn_mfma_f32_32x32x16_bf16(a, b, c, 0, 0, 0);
}
__device__ __forceinline__ float hexp2(float x) { return __builtin_amdgcn_exp2f(x); }

// Tiled layouts: X_t[b][h][tile][row32][ch32], 1024 bf16/tile -> flash fragment
// loads are contiguous 2KB slabs (r14 win: 92->69us, L2-line scatter removed).

// ---- one-shot setup: pack 4 weights to bf16, BN scale/shift, PE table ----
__global__ __launch_bounds__(256) void setup_kernel(
    const float* __restrict__ gamma, const float* __restrict__ beta,
    const float* __restrict__ rmean, const float* __restrict__ rvar,
    const float* __restrict__ w0, const float* __restrict__ w1,
    const float* __restrict__ w2, const float* __restrict__ w3,
    float* __restrict__ bninv, float* __restrict__ bnshift, float* __restrict__ PEt,
    __hip_bfloat16* __restrict__ o0, __hip_bfloat16* __restrict__ o1,
    __hip_bfloat16* __restrict__ o2, __hip_bfloat16* __restrict__ o3) {
    int bid = blockIdx.x, t = threadIdx.x;
    if (bid < 256) {            // weight packing: weight bid>>6, chunk bid&63
        int wi = bid >> 6;
        const float* w = wi == 0 ? w0 : wi == 1 ? w1 : wi == 2 ? w2 : w3;
        __hip_bfloat16* o = wi == 0 ? o0 : wi == 1 ? o1 : wi == 2 ? o2 : o3;
        int idx = ((bid & 63) * 256 + t) * 4;
        float4 v = *reinterpret_cast<const float4*>(w + idx);
        o[idx]     = __float2bfloat16(v.x);
        o[idx + 1] = __float2bfloat16(v.y);
        o[idx + 2] = __float2bfloat16(v.z);
        o[idx + 3] = __float2bfloat16(v.w);
    } else if (bid == 256) {    // BN scale/shift
        float iv = gamma[t] / sqrtf(rvar[t] + 1e-5f);
        bninv[t] = iv;
        bnshift[t] = beta[t] - rmean[t] * iv;
    } else {                    // PE table [pos][c], pos = bid-257 (48 blocks)
        int pos = bid - 257;
        int cc = (t < 128) ? t : (t - 128);
        float dv = __expf((float)(cc & ~1) * (float)(-9.210340371976184 / 128.0));
        float pd = (float)pos * dv;
        float rv = (t & 1) ? cosf(pd) : sinf(pd);
        const float RINV = 1.0f / sqrtf(128.0f + 1e-6f);
        PEt[pos * 256 + t] = rv * RINV;
    }
}

// ---- xn^T: (B,C,M) fp32 + BN -> (B,M,C) bf16 ------------------------------
__global__ __launch_bounds__(256) void xnt_kernel(const float* __restrict__ x,
                                                  const float* __restrict__ bninv,
                                                  const float* __restrict__ bnshift,
                                                  __hip_bfloat16* __restrict__ Xnt) {
    __shared__ float T[64][65];
    int t = threadIdx.x;
    int m0 = blockIdx.x * 64, c0 = blockIdx.y * 64, b = blockIdx.z;
    int ml = t & 63;
    #pragma unroll
    for (int i = 0; i < 16; i++) {
        int c = (t >> 6) + i * 4;
        T[c][ml] = x[(size_t)(b * kC + c0 + c) * kM + m0 + ml] * bninv[c0 + c] + bnshift[c0 + c];
    }
    __syncthreads();
    int mr = t >> 2, cseg = (t & 3) * 16;
    __hip_bfloat16 v[16];
    #pragma unroll
    for (int j = 0; j < 16; j++) v[j] = __float2bfloat16(T[cseg + j][mr]);
    __hip_bfloat16* dst = Xnt + (size_t)(b * kM + m0 + mr) * kC + c0 + cseg;
    *reinterpret_cast<bf16x8*>(dst)     = *reinterpret_cast<bf16x8*>(&v[0]);
    *reinterpret_cast<bf16x8*>(dst + 8) = *reinterpret_cast<bf16x8*>(&v[8]);
}

// ---- fused-BN 1x1 convs as bf16 MFMA GEMM: 1 wave = 16m x 32o, one matrix -
// (32o per wave -> 6912 waves, 2x r14's grid: conv was wave-starved at 3.4/SIMD)
__global__ __launch_bounds__(64) void conv_gemm(const __hip_bfloat16* __restrict__ Xnt,
                                                const __hip_bfloat16* __restrict__ Wv,
                                                const __hip_bfloat16* __restrict__ Wz,
                                                const __hip_bfloat16* __restrict__ Wq,
                                                __hip_bfloat16* __restrict__ Vt,
                                                __hip_bfloat16* __restrict__ Zb16,
                                                __hip_bfloat16* __restrict__ Qtt) {
    int t = threadIdx.x, li = t & 15, g = t >> 4;
    int m0 = blockIdx.x * 16, o0 = blockIdx.y * 32;
    int mat = blockIdx.z >> 1, b = blockIdx.z & 1;
    const __hip_bfloat16* W = mat == 0 ? Wv : mat == 1 ? Wz : Wq;

    bf16x8 a[8];
    const __hip_bfloat16* ap = Xnt + (size_t)(b * kM + m0 + li) * kC + g * 8;
    #pragma unroll
    for (int kb = 0; kb < 8; kb++) a[kb] = *reinterpret_cast<const bf16x8*>(ap + kb * 32);

    f32x4 acc[2] = {{0,0,0,0},{0,0,0,0}};
    const __hip_bfloat16* wp = W + g * 8;
    #pragma unroll
    for (int kb = 0; kb < 8; kb++) {
        #pragma unroll
        for (int ot = 0; ot < 2; ot++) {
            bf16x8 bw = *reinterpret_cast<const bf16x8*>(wp + (size_t)(o0 + ot * 16 + li) * kC + kb * 32);
            acc[ot] = mfma16(a[kb], bw, acc[ot]);
        }
    }

    const int mt = m0 >> 5;            // tile index
    const int mmb = m0 & 31;           // row offset within tile
    const int hh = o0 >> 5;            // head (o0 multiple of 32)
    if (mat == 0) {
        // V prescale: (1/sqrt(32)) * log2(e)  -> softmax uses exp2 directly
        const float SCALE2 = 0.25501988169885635f;
        #pragma unroll
        for (int ot = 0; ot < 2; ot++) {
            int cc = (o0 + ot * 16 + li) & 31;
            __hip_bfloat16* base = Vt + (((size_t)(b * kH + hh) * kNT + mt) * 32) * 32 + cc;
            #pragma unroll
            for (int r = 0; r < 4; r++)
                base[(mmb + 4 * g + r) * 32] = __float2bfloat16(acc[ot][r] * SCALE2);
        }
    } else if (mat == 1) {
        #pragma unroll
        for (int ot = 0; ot < 2; ot++)
            #pragma unroll
            for (int r = 0; r < 4; r++)
                Zb16[(size_t)(b * kM + m0 + 4 * g + r) * kC + o0 + ot * 16 + li] = __float2bfloat16(acc[ot][r]);
    } else {
        #pragma unroll
        for (int ot = 0; ot < 2; ot++) {
            int d = (o0 + ot * 16 + li) & 31;
            __hip_bfloat16* base = Qtt + (((size_t)(b * kH + hh) * kNT + mt) * 32 + d) * 32 + mmb + 4 * g;
            *reinterpret_cast<__hip_bfloat162*>(base) =
                __float22bfloat162_rn(make_float2(acc[ot][0], acc[ot][1]));
            *reinterpret_cast<__hip_bfloat162*>(base + 2) =
                __float22bfloat162_rn(make_float2(acc[ot][2], acc[ot][3]));
        }
    }
}

// ---- zr = l2n(z) + l2n(r): 4 tokens/block, 1 wave/token -> ZRt tiled -----
__global__ __launch_bounds__(256) void zr_kernel(const __hip_bfloat16* __restrict__ Z,
                                                 const float* __restrict__ PEt,
                                                 __hip_bfloat16* __restrict__ ZRt) {
    int t = threadIdx.x;
    int bm = blockIdx.x * 4 + (t >> 6);   // token
    int lane = t & 63;                     // 4 channels each
    int m = bm % kM, b = bm / kM;
    union { uint2 u; __hip_bfloat16 h[4]; } zu;
    zu.u = *reinterpret_cast<const uint2*>(Z + (size_t)bm * kC + lane * 4);
    float z[4];
    #pragma unroll
    for (int j = 0; j < 4; j++) z[j] = __bfloat162float(zu.h[j]);
    float ss = (z[0]*z[0] + z[1]*z[1]) + (z[2]*z[2] + z[3]*z[3]);
    #pragma unroll
    for (int k = 32; k >= 1; k >>= 1) ss += __shfl_xor(ss, k);
    float zinv = 1.0f / sqrtf(ss + 1e-6f);
    int pos = (lane < 32) ? (m % kW) : (m / kW);
    f32x4 pe = *reinterpret_cast<const f32x4*>(PEt + pos * 256 + lane * 4);
    union { uint2 u; __hip_bfloat16 h[4]; } ou;
    #pragma unroll
    for (int j = 0; j < 4; j++) ou.h[j] = __float2bfloat16(z[j] * zinv + pe[j]);
    int hh = lane >> 3, cc = (lane * 4) & 31;
    *reinterpret_cast<uint2*>(
        ZRt + (((size_t)(b * kH + hh) * kNT + (m >> 5)) * 32 + (m & 31)) * 32 + cc) = ou.u;
}

// ---- fused flash attention on tiled layouts, software-pipelined ----------
// Flat 1152-block grid, XCD decode: bh = blk & 15, mtile = blk >> 4.
// 8 waves/block; wave w owns KV tiles [w*9, w*9+9).
// 2-stage pipeline: loads 2 tiles ahead, QK(it+1) on MFMA pipe overlaps
// exp/pack(it) on VALU pipe (separate pipes co-issue, m114).
// PV B-frag via cvt_pk + v_permlane32_swap (vdst.hi <-> vsrc.lo, r10/r11).
// No max-tracking (|logit*log2e| <~ 33; exp2 fp32-safe). Epilogue LDS combine.
__global__ __launch_bounds__(512) void flash_attn_fused(
    const __hip_bfloat16* __restrict__ Vt,   // (B,H,72,32m,32c) prescaled
    const __hip_bfloat16* __restrict__ ZRt,  // (B,H,72,32n,32c)
    const __hip_bfloat16* __restrict__ Qtt,  // (B,H,72,32d,32n)
    __hip_bfloat16* __restrict__ Y16)        // (B,M,C)
{
    __shared__ float Aw[8][32 * 36];   // per-wave Y^T partial, [m][dh] pitch 36
    __shared__ float Ls[8][64];        // per-wave per-lane lsum partials
    const int t = threadIdx.x;
    const int w = t >> 6, lane = t & 63;
    const int c = lane & 31, hi = lane >> 5;
    const int blk = blockIdx.x;
    const int bh = blk & 15, mtile = blk >> 4;
    const int b = bh >> 3, h = bh & 7;
    const int m0 = mtile * 32;
    const f32x16 zero16 = {0,0,0,0,0,0,0,0,0,0,0,0,0,0,0,0};

    const int lo = c * 32 + hi * 8;    // lane offset within a 1024-elem tile
    const size_t hb = (size_t)bh * kNT;

    const __hip_bfloat16* vb = Vt + (hb + mtile) * 1024 + lo;
    bf16x8 vf0 = *reinterpret_cast<const bf16x8*>(vb);
    bf16x8 vf1 = *reinterpret_cast<const bf16x8*>(vb + 16);

    const __hip_bfloat16* zb = ZRt + (hb + w * 9) * 1024 + lo;   // walk +1024/iter
    const __hip_bfloat16* qb = Qtt + (hb + w * 9) * 1024 + lo;

    f32x16 acc = zero16;
    float lsum = 0.f;

    // ---- pipeline prologue ----
    // tile 0 regs + QK(0); tile 1 regs in flight
    bf16x8 zC0 = *reinterpret_cast<const bf16x8*>(zb);
    bf16x8 zC1 = *reinterpret_cast<const bf16x8*>(zb + 16);
    bf16x8 qC0 = *reinterpret_cast<const bf16x8*>(qb);
    bf16x8 qC1 = *reinterpret_cast<const bf16x8*>(qb + 16);
    bf16x8 zA0 = *reinterpret_cast<const bf16x8*>(zb + 1024);
    bf16x8 zA1 = *reinterpret_cast<const bf16x8*>(zb + 1024 + 16);
    bf16x8 qA0 = *reinterpret_cast<const bf16x8*>(qb + 1024);
    bf16x8 qA1 = *reinterpret_cast<const bf16x8*>(qb + 1024 + 16);
    f32x16 stC = mfma32(zC0, vf0, zero16);
    stC = mfma32(zC1, vf1, stC);

    for (int it = 0; it < 9; ++it) {
        // loads for it+2 (wrap harmless)
        const int nx2 = (it + 2 < 9) ? (it + 2) * 1024 : 0;
        bf16x8 zN0 = *reinterpret_cast<const bf16x8*>(zb + nx2);
        bf16x8 zN1 = *reinterpret_cast<const bf16x8*>(zb + nx2 + 16);
        bf16x8 qN0 = *reinterpret_cast<const bf16x8*>(qb + nx2);
        bf16x8 qN1 = *reinterpret_cast<const bf16x8*>(qb + nx2 + 16);

        // QK for it+1 on the MFMA pipe (regs loaded last iter; result garbage
        // on final iter, discarded)
        f32x16 stN = mfma32(zA0, vf0, zero16);
        stN = mfma32(zA1, vf1, stN);

        // exp/pack/PV for it on the VALU pipe (overlaps stN's MFMAs)
        float p[16];
        #pragma unroll
        for (int r = 0; r < 16; r++) p[r] = hexp2(stC[r]);
        float s01 = (p[0] + p[1]) + (p[2] + p[3]);
        float s23 = (p[4] + p[5]) + (p[6] + p[7]);
        float s45 = (p[8] + p[9]) + (p[10] + p[11]);
        float s67 = (p[12] + p[13]) + (p[14] + p[15]);
        lsum += (s01 + s23) + (s45 + s67);

        #pragma unroll
        for (int kk = 0; kk < 2; kk++) {
            __hip_bfloat162 xw0 = __float22bfloat162_rn(make_float2(p[8*kk+0], p[8*kk+1]));
            __hip_bfloat162 xw1 = __float22bfloat162_rn(make_float2(p[8*kk+2], p[8*kk+3]));
            __hip_bfloat162 yw0 = __float22bfloat162_rn(make_float2(p[8*kk+4], p[8*kk+5]));
            __hip_bfloat162 yw1 = __float22bfloat162_rn(make_float2(p[8*kk+6], p[8*kk+7]));
            unsigned x0 = *reinterpret_cast<unsigned*>(&xw0);
            unsigned x1 = *reinterpret_cast<unsigned*>(&xw1);
            unsigned y0 = *reinterpret_cast<unsigned*>(&yw0);
            unsigned y1 = *reinterpret_cast<unsigned*>(&yw1);
            // vdst.hi <-> vsrc.lo: hi=0: {own x, partner x}; hi=1: {partner y, own y}
            asm("v_permlane32_swap_b32 %0, %1" : "+v"(x0), "+v"(y0));
            asm("v_permlane32_swap_b32 %0, %1" : "+v"(x1), "+v"(y1));
            union { unsigned u[4]; bf16x8 v; } bf;
            bf.u[0] = x0; bf.u[1] = x1; bf.u[2] = y0; bf.u[3] = y1;
            acc = mfma32(kk == 0 ? qC0 : qC1, bf.v, acc);
        }

        // rotate pipeline registers
        stC = stN;
        qC0 = qA0; qC1 = qA1;
        zA0 = zN0; zA1 = zN1; qA0 = qN0; qA1 = qN1;
    }

    // epilogue: stage partials, combine across the 8 waves
    #pragma unroll
    for (int r = 0; r < 16; r++) {
        int dh = (r & 3) + 8 * (r >> 2) + 4 * hi;
        Aw[w][c * 36 + dh] = acc[r];
    }
    Ls[w][lane] = lsum;
    __syncthreads();

    if (t < 256) {   // 32 m-rows x 8 dh-groups of 4
        const int m = t & 31, dh0 = (t >> 5) * 4;
        float L = 0.f;
        #pragma unroll
        for (int w2 = 0; w2 < 8; w2++) L += Ls[w2][m] + Ls[w2][m + 32];
        f32x4 s4 = {0.f, 0.f, 0.f, 0.f};
        #pragma unroll
        for (int w2 = 0; w2 < 8; w2++)
            s4 = s4 + *reinterpret_cast<const f32x4*>(&Aw[w2][m * 36 + dh0]);
        float inv = 1.0f / L;
        union { uint2 u2; __hip_bfloat162 h2[2]; } o;
        o.h2[0] = __float22bfloat162_rn(make_float2(s4[0] * inv, s4[1] * inv));
        o.h2[1] = __float22bfloat162_rn(make_float2(s4[2] * inv, s4[3] * inv));
        *reinterpret_cast<uint2*>(Y16 + (size_t)(b * kM + m0 + m) * kC + h * kDH + dh0) = o.u2;
    }
}

// ---- output conv as bf16 MFMA GEMM: 1 wave = 16m x 32o (2304 waves) -------
__global__ __launch_bounds__(64) void conv_out_gemm(const __hip_bfloat16* __restrict__ Y16,
                                                    const __hip_bfloat16* __restrict__ Wo,
                                                    float* __restrict__ out) {
    int t = threadIdx.x, li = t & 15, g = t >> 4;
    int m0 = blockIdx.x * 16, o0 = blockIdx.y * 32, b = blockIdx.z;

    bf16x8 a[8];
    const __hip_bfloat16* ap = Y16 + (size_t)(b * kM + m0 + li) * kC + g * 8;
    #pragma unroll
    for (int kb = 0; kb < 8; kb++) a[kb] = *reinterpret_cast<const bf16x8*>(ap + kb * 32);

    f32x4 acc[2] = {{0,0,0,0},{0,0,0,0}};
    const __hip_bfloat16* wp = Wo + g * 8;
    #pragma unroll
    for (int kb = 0; kb < 8; kb++) {
        #pragma unroll
        for (int ot = 0; ot < 2; ot++) {
            bf16x8 bw = *reinterpret_cast<const bf16x8*>(wp + (size_t)(o0 + ot * 16 + li) * kC + kb * 32);
            acc[ot] = mfma16(a[kb], bw, acc[ot]);
        }
    }
    #pragma unroll
    for (int ot = 0; ot < 2; ot++) {
        int o = o0 + ot * 16 + li;
        *reinterpret_cast<f32x4*>(out + (size_t)(b * kC + o) * kM + m0 + 4 * g) = acc[ot];
    }
}

extern "C" void kernel_launch(void* const* d_in, const int* in_sizes, int n_in,
                              void* d_out, int out_size, void* d_ws, size_t ws_size,
                              hipStream_t stream) {
    const float* x     = (const float*)d_in[0];
    const float* gamma = (const float*)d_in[1];
    const float* beta  = (const float*)d_in[2];
    const float* rmean = (const float*)d_in[3];
    const float* rvar  = (const float*)d_in[4];
    const float* v_w   = (const float*)d_in[5];
    const float* z_w   = (const float*)d_in[6];
    const float* q_w   = (const float*)d_in[7];
    const float* o_w   = (const float*)d_in[8];
    float* out = (float*)d_out;

    char* wsb = (char*)d_ws;
    const size_t BMC = (size_t)kB * kM * kC;    // 1,179,648
    float* bninv   = (float*)wsb;               // [0, 1024)
    float* bnshift = (float*)(wsb + 1024);      // [1024, 2048)
    float* PEt     = (float*)(wsb + 4096);      // [pos][c], 49152 B -> ends 53248
    __hip_bfloat16* Wv16 = (__hip_bfloat16*)(wsb + 53248);
    __hip_bfloat16* Wz16 = Wv16 + 65536;
    __hip_bfloat16* Wq16 = Wz16 + 65536;
    __hip_bfloat16* Wo16 = Wq16 + 65536;
    __hip_bfloat16* Xnt  = Wo16 + 65536;
    __hip_bfloat16* Vt   = Xnt + BMC;           // tiled (B,H,72,32,32)
    __hip_bfloat16* Zb16 = Vt + BMC;            // (B,M,C)
    __hip_bfloat16* ZRt  = Zb16 + BMC;          // tiled
    __hip_bfloat16* Qtt  = ZRt + BMC;           // tiled
    __hip_bfloat16* Y16  = Qtt + BMC;           // (B,M,C); total ~14.7 MB

    setup_kernel<<<dim3(305), dim3(256), 0, stream>>>(
        gamma, beta, rmean, rvar, v_w, z_w, q_w, o_w,
        bninv, bnshift, PEt, Wv16, Wz16, Wq16, Wo16);
    xnt_kernel<<<dim3(kM / 64, kC / 64, kB), dim3(256), 0, stream>>>(x, bninv, bnshift, Xnt);
    conv_gemm<<<dim3(kM / 16, kC / 32, 3 * kB), dim3(64), 0, stream>>>(
        Xnt, Wv16, Wz16, Wq16, Vt, Zb16, Qtt);
    zr_kernel<<<dim3(kB * kM / 4), dim3(256), 0, stream>>>(Zb16, PEt, ZRt);
    flash_attn_fused<<<dim3(kNT * kH * kB), dim3(512), 0, stream>>>(Vt, ZRt, Qtt, Y16);
    conv_out_gemm<<<dim3(kM / 16, kC / 32, kB), dim3(64), 0, stream>>>(Y16, Wo16, out);
}

// Round 16
// 70.530 us; speedup vs baseline: 1.0385x; 1.0385x over previous
//
#include <hip/hip_runtime.h>
#include <hip/hip_bf16.h>
#include <math.h>

namespace {
constexpr int kC  = 256;   // channels
constexpr int kW  = 48;    // width
constexpr int kM  = 2304;  // tokens = 48*48
constexpr int kB  = 2;     // batch
constexpr int kDH = 32;    // head dim
constexpr int kH  = 8;     // heads
constexpr int kNT = kM / 32;  // 72 tiles of 32 tokens
}

typedef float  f32x4   __attribute__((ext_vector_type(4)));
typedef float  f32x16  __attribute__((ext_vector_type(16)));
typedef __bf16 bf16x8  __attribute__((ext_vector_type(8)));

// 16x16x32: A row=lane&15 ; B col=lane&15 ; D col=lane&15, row=(lane>>4)*4+reg
__device__ __forceinline__ f32x4 mfma16(bf16x8 a, bf16x8 b, f32x4 c) {
    return __builtin_amdgcn_mfma_f32_16x16x32_bf16(a, b, c, 0, 0, 0);
}
// 32x32x16: A row=lane&31 ; B col=lane&31 ; D col=lane&31, row=(reg&3)+8*(reg>>2)+4*(lane>>5)
__device__ __forceinline__ f32x16 mfma32(bf16x8 a, bf16x8 b, f32x16 c) {
    return __builtin_amdgcn_mfma_f32_32x32x16_bf16(a, b, c, 0, 0, 0);
}
__device__ __forceinline__ float hexp2(float x) { return __builtin_amdgcn_exp2f(x); }

// Tiled layouts: X_t[b][h][tile][row32][ch32], 1024 bf16/tile -> flash fragment
// loads are contiguous 2KB slabs (r14 win: 92->69us, L2-line scatter removed).

// ---- one-shot setup: pack 4 weights to bf16, BN scale/shift, PE table ----
__global__ __launch_bounds__(256) void setup_kernel(
    const float* __restrict__ gamma, const float* __restrict__ beta,
    const float* __restrict__ rmean, const float* __restrict__ rvar,
    const float* __restrict__ w0, const float* __restrict__ w1,
    const float* __restrict__ w2, const float* __restrict__ w3,
    float* __restrict__ bninv, float* __restrict__ bnshift, float* __restrict__ PEt,
    __hip_bfloat16* __restrict__ o0, __hip_bfloat16* __restrict__ o1,
    __hip_bfloat16* __restrict__ o2, __hip_bfloat16* __restrict__ o3) {
    int bid = blockIdx.x, t = threadIdx.x;
    if (bid < 256) {            // weight packing: weight bid>>6, chunk bid&63
        int wi = bid >> 6;
        const float* w = wi == 0 ? w0 : wi == 1 ? w1 : wi == 2 ? w2 : w3;
        __hip_bfloat16* o = wi == 0 ? o0 : wi == 1 ? o1 : wi == 2 ? o2 : o3;
        int idx = ((bid & 63) * 256 + t) * 4;
        float4 v = *reinterpret_cast<const float4*>(w + idx);
        o[idx]     = __float2bfloat16(v.x);
        o[idx + 1] = __float2bfloat16(v.y);
        o[idx + 2] = __float2bfloat16(v.z);
        o[idx + 3] = __float2bfloat16(v.w);
    } else if (bid == 256) {    // BN scale/shift
        float iv = gamma[t] / sqrtf(rvar[t] + 1e-5f);
        bninv[t] = iv;
        bnshift[t] = beta[t] - rmean[t] * iv;
    } else {                    // PE table [pos][c], pos = bid-257 (48 blocks)
        int pos = bid - 257;
        int cc = (t < 128) ? t : (t - 128);
        float dv = __expf((float)(cc & ~1) * (float)(-9.210340371976184 / 128.0));
        float pd = (float)pos * dv;
        float rv = (t & 1) ? cosf(pd) : sinf(pd);
        const float RINV = 1.0f / sqrtf(128.0f + 1e-6f);
        PEt[pos * 256 + t] = rv * RINV;
    }
}

// ---- xn^T: (B,C,M) fp32 + BN -> (B,M,C) bf16 ------------------------------
__global__ __launch_bounds__(256) void xnt_kernel(const float* __restrict__ x,
                                                  const float* __restrict__ bninv,
                                                  const float* __restrict__ bnshift,
                                                  __hip_bfloat16* __restrict__ Xnt) {
    __shared__ float T[64][65];
    int t = threadIdx.x;
    int m0 = blockIdx.x * 64, c0 = blockIdx.y * 64, b = blockIdx.z;
    int ml = t & 63;
    #pragma unroll
    for (int i = 0; i < 16; i++) {
        int c = (t >> 6) + i * 4;
        T[c][ml] = x[(size_t)(b * kC + c0 + c) * kM + m0 + ml] * bninv[c0 + c] + bnshift[c0 + c];
    }
    __syncthreads();
    int mr = t >> 2, cseg = (t & 3) * 16;
    __hip_bfloat16 v[16];
    #pragma unroll
    for (int j = 0; j < 16; j++) v[j] = __float2bfloat16(T[cseg + j][mr]);
    __hip_bfloat16* dst = Xnt + (size_t)(b * kM + m0 + mr) * kC + c0 + cseg;
    *reinterpret_cast<bf16x8*>(dst)     = *reinterpret_cast<bf16x8*>(&v[0]);
    *reinterpret_cast<bf16x8*>(dst + 8) = *reinterpret_cast<bf16x8*>(&v[8]);
}

// ---- fused-BN 1x1 convs as bf16 MFMA GEMM: 1 wave = 16m x 64o, one matrix -
// mat 0 -> Vt tiled (prescaled log2e/sqrt32); mat 1 -> Zb16 (B,M,C); mat 2 -> Qtt tiled
__global__ __launch_bounds__(64) void conv_gemm(const __hip_bfloat16* __restrict__ Xnt,
                                                const __hip_bfloat16* __restrict__ Wv,
                                                const __hip_bfloat16* __restrict__ Wz,
                                                const __hip_bfloat16* __restrict__ Wq,
                                                __hip_bfloat16* __restrict__ Vt,
                                                __hip_bfloat16* __restrict__ Zb16,
                                                __hip_bfloat16* __restrict__ Qtt) {
    int t = threadIdx.x, li = t & 15, g = t >> 4;
    int m0 = blockIdx.x * 16, o0 = blockIdx.y * 64;
    int mat = blockIdx.z >> 1, b = blockIdx.z & 1;
    const __hip_bfloat16* W = mat == 0 ? Wv : mat == 1 ? Wz : Wq;

    bf16x8 a[8];
    const __hip_bfloat16* ap = Xnt + (size_t)(b * kM + m0 + li) * kC + g * 8;
    #pragma unroll
    for (int kb = 0; kb < 8; kb++) a[kb] = *reinterpret_cast<const bf16x8*>(ap + kb * 32);

    f32x4 acc[4] = {{0,0,0,0},{0,0,0,0},{0,0,0,0},{0,0,0,0}};
    const __hip_bfloat16* wp = W + g * 8;
    #pragma unroll
    for (int kb = 0; kb < 8; kb++) {
        #pragma unroll
        for (int ot = 0; ot < 4; ot++) {
            bf16x8 bw = *reinterpret_cast<const bf16x8*>(wp + (size_t)(o0 + ot * 16 + li) * kC + kb * 32);
            acc[ot] = mfma16(a[kb], bw, acc[ot]);
        }
    }

    const int mt = m0 >> 5;            // tile index
    const int mmb = m0 & 31;           // row offset within tile
    if (mat == 0) {
        // V prescale: (1/sqrt(32)) * log2(e)  -> softmax uses exp2 directly
        const float SCALE2 = 0.25501988169885635f;
        #pragma unroll
        for (int ot = 0; ot < 4; ot++) {
            int o = o0 + ot * 16 + li, hh = o >> 5, cc = o & 31;
            __hip_bfloat16* base = Vt + (((size_t)(b * kH + hh) * kNT + mt) * 32) * 32 + cc;
            #pragma unroll
            for (int r = 0; r < 4; r++)
                base[(mmb + 4 * g + r) * 32] = __float2bfloat16(acc[ot][r] * SCALE2);
        }
    } else if (mat == 1) {
        #pragma unroll
        for (int ot = 0; ot < 4; ot++)
            #pragma unroll
            for (int r = 0; r < 4; r++)
                Zb16[(size_t)(b * kM + m0 + 4 * g + r) * kC + o0 + ot * 16 + li] = __float2bfloat16(acc[ot][r]);
    } else {
        #pragma unroll
        for (int ot = 0; ot < 4; ot++) {
            int o = o0 + ot * 16 + li, hh = o >> 5, d = o & 31;
            __hip_bfloat16* base = Qtt + (((size_t)(b * kH + hh) * kNT + mt) * 32 + d) * 32 + mmb + 4 * g;
            *reinterpret_cast<__hip_bfloat162*>(base) =
                __float22bfloat162_rn(make_float2(acc[ot][0], acc[ot][1]));
            *reinterpret_cast<__hip_bfloat162*>(base + 2) =
                __float22bfloat162_rn(make_float2(acc[ot][2], acc[ot][3]));
        }
    }
}

// ---- zr = l2n(z) + l2n(r): 4 tokens/block, 1 wave/token -> ZRt tiled -----
__global__ __launch_bounds__(256) void zr_kernel(const __hip_bfloat16* __restrict__ Z,
                                                 const float* __restrict__ PEt,
                                                 __hip_bfloat16* __restrict__ ZRt) {
    int t = threadIdx.x;
    int bm = blockIdx.x * 4 + (t >> 6);   // token
    int lane = t & 63;                     // 4 channels each
    int m = bm % kM, b = bm / kM;
    union { uint2 u; __hip_bfloat16 h[4]; } zu;
    zu.u = *reinterpret_cast<const uint2*>(Z + (size_t)bm * kC + lane * 4);
    float z[4];
    #pragma unroll
    for (int j = 0; j < 4; j++) z[j] = __bfloat162float(zu.h[j]);
    float ss = (z[0]*z[0] + z[1]*z[1]) + (z[2]*z[2] + z[3]*z[3]);
    #pragma unroll
    for (int k = 32; k >= 1; k >>= 1) ss += __shfl_xor(ss, k);
    float zinv = 1.0f / sqrtf(ss + 1e-6f);
    int pos = (lane < 32) ? (m % kW) : (m / kW);
    f32x4 pe = *reinterpret_cast<const f32x4*>(PEt + pos * 256 + lane * 4);
    union { uint2 u; __hip_bfloat16 h[4]; } ou;
    #pragma unroll
    for (int j = 0; j < 4; j++) ou.h[j] = __float2bfloat16(z[j] * zinv + pe[j]);
    int hh = lane >> 3, cc = (lane * 4) & 31;
    *reinterpret_cast<uint2*>(
        ZRt + (((size_t)(b * kH + hh) * kNT + (m >> 5)) * 32 + (m & 31)) * 32 + cc) = ou.u;
}

// ---- fused flash attention on tiled layouts, 16 waves/block --------------
// Flat 1152-block grid, XCD decode: bh = blk & 15, mtile = blk >> 4 (16=0 mod 8
// -> all 72 blocks of a (b,h) on one XCD, L2-resident slice).
// 16 waves/block (1024 thr): waves 0-7 own 5 KV tiles, waves 8-15 own 4
// (72 total) -> per-wave serial chain HALVED vs r14's 9 tiles/wave, wave
// count doubled to 18432 for latency hiding. 1-deep register prefetch.
// PV B-frag via cvt_pk + v_permlane32_swap (vdst.hi <-> vsrc.lo, r10/r11).
// No max-tracking (|logit*log2e| <~ 33; exp2 fp32-safe). Epilogue LDS combine.
__global__ __launch_bounds__(1024) void flash_attn_fused(
    const __hip_bfloat16* __restrict__ Vt,   // (B,H,72,32m,32c) prescaled
    const __hip_bfloat16* __restrict__ ZRt,  // (B,H,72,32n,32c)
    const __hip_bfloat16* __restrict__ Qtt,  // (B,H,72,32d,32n)
    __hip_bfloat16* __restrict__ Y16)        // (B,M,C)
{
    __shared__ float Aw[16][32 * 36];  // per-wave Y^T partial, [m][dh] pitch 36 (73728 B)
    __shared__ float Ls[16][64];       // per-wave per-lane lsum partials         (4096 B)
    const int t = threadIdx.x;
    const int w = t >> 6, lane = t & 63;
    const int c = lane & 31, hi = lane >> 5;
    const int blk = blockIdx.x;
    const int bh = blk & 15, mtile = blk >> 4;
    const int b = bh >> 3, h = bh & 7;
    const int m0 = mtile * 32;
    const f32x16 zero16 = {0,0,0,0,0,0,0,0,0,0,0,0,0,0,0,0};

    const int lo = c * 32 + hi * 8;    // lane offset within a 1024-elem tile
    const size_t hb = (size_t)bh * kNT;

    const __hip_bfloat16* vb = Vt + (hb + mtile) * 1024 + lo;
    bf16x8 vf0 = *reinterpret_cast<const bf16x8*>(vb);
    bf16x8 vf1 = *reinterpret_cast<const bf16x8*>(vb + 16);

    // wave w's KV tile range: w<8 -> [5w, 5w+5) ; w>=8 -> [40+4(w-8), +4)
    const int nt = (w < 8) ? 5 : 4;
    const int t0 = (w < 8) ? w * 5 : 40 + (w - 8) * 4;
    const __hip_bfloat16* zb = ZRt + (hb + t0) * 1024 + lo;   // walk +1024/iter
    const __hip_bfloat16* qb = Qtt + (hb + t0) * 1024 + lo;

    f32x16 acc = zero16;
    float lsum = 0.f;

    bf16x8 za0 = *reinterpret_cast<const bf16x8*>(zb);
    bf16x8 za1 = *reinterpret_cast<const bf16x8*>(zb + 16);
    bf16x8 qa0 = *reinterpret_cast<const bf16x8*>(qb);
    bf16x8 qa1 = *reinterpret_cast<const bf16x8*>(qb + 16);

    for (int it = 0; it < nt; ++it) {
        const int nx = (it + 1 < nt) ? (it + 1) * 1024 : 0;   // harmless wrap

        // QK^T
        f32x16 st = mfma32(za0, vf0, zero16);
        st = mfma32(za1, vf1, st);

        // prefetch next tile's fragments (contiguous 2KB slabs)
        bf16x8 za0n = *reinterpret_cast<const bf16x8*>(zb + nx);
        bf16x8 za1n = *reinterpret_cast<const bf16x8*>(zb + nx + 16);
        bf16x8 qa0n = *reinterpret_cast<const bf16x8*>(qb + nx);
        bf16x8 qa1n = *reinterpret_cast<const bf16x8*>(qb + nx + 16);

        // raw exp2 (no max subtraction), tree sum
        float p[16];
        #pragma unroll
        for (int r = 0; r < 16; r++) p[r] = hexp2(st[r]);
        float s01 = (p[0] + p[1]) + (p[2] + p[3]);
        float s23 = (p[4] + p[5]) + (p[6] + p[7]);
        float s45 = (p[8] + p[9]) + (p[10] + p[11]);
        float s67 = (p[12] + p[13]) + (p[14] + p[15]);
        lsum += (s01 + s23) + (s45 + s67);

        // PV: two K=16 MFMAs; B-frags via cvt_pk + permlane32_swap
        #pragma unroll
        for (int kk = 0; kk < 2; kk++) {
            __hip_bfloat162 xw0 = __float22bfloat162_rn(make_float2(p[8*kk+0], p[8*kk+1]));
            __hip_bfloat162 xw1 = __float22bfloat162_rn(make_float2(p[8*kk+2], p[8*kk+3]));
            __hip_bfloat162 yw0 = __float22bfloat162_rn(make_float2(p[8*kk+4], p[8*kk+5]));
            __hip_bfloat162 yw1 = __float22bfloat162_rn(make_float2(p[8*kk+6], p[8*kk+7]));
            unsigned x0 = *reinterpret_cast<unsigned*>(&xw0);
            unsigned x1 = *reinterpret_cast<unsigned*>(&xw1);
            unsigned y0 = *reinterpret_cast<unsigned*>(&yw0);
            unsigned y1 = *reinterpret_cast<unsigned*>(&yw1);
            // vdst.hi <-> vsrc.lo: hi=0: {own x, partner x}; hi=1: {partner y, own y}
            asm("v_permlane32_swap_b32 %0, %1" : "+v"(x0), "+v"(y0));
            asm("v_permlane32_swap_b32 %0, %1" : "+v"(x1), "+v"(y1));
            union { unsigned u[4]; bf16x8 v; } bf;
            bf.u[0] = x0; bf.u[1] = x1; bf.u[2] = y0; bf.u[3] = y1;
            acc = mfma32(kk == 0 ? qa0 : qa1, bf.v, acc);
        }

        za0 = za0n; za1 = za1n; qa0 = qa0n; qa1 = qa1n;
    }

    // epilogue: stage partials, combine across the 16 waves
    #pragma unroll
    for (int r = 0; r < 16; r++) {
        int dh = (r & 3) + 8 * (r >> 2) + 4 * hi;
        Aw[w][c * 36 + dh] = acc[r];
    }
    Ls[w][lane] = lsum;
    __syncthreads();

    if (t < 256) {   // 32 m-rows x 8 dh-groups of 4
        const int m = t & 31, dh0 = (t >> 5) * 4;
        float L = 0.f;
        #pragma unroll
        for (int w2 = 0; w2 < 16; w2++) L += Ls[w2][m] + Ls[w2][m + 32];
        f32x4 s4 = {0.f, 0.f, 0.f, 0.f};
        #pragma unroll
        for (int w2 = 0; w2 < 16; w2++)
            s4 = s4 + *reinterpret_cast<const f32x4*>(&Aw[w2][m * 36 + dh0]);
        float inv = 1.0f / L;
        union { uint2 u2; __hip_bfloat162 h2[2]; } o;
        o.h2[0] = __float22bfloat162_rn(make_float2(s4[0] * inv, s4[1] * inv));
        o.h2[1] = __float22bfloat162_rn(make_float2(s4[2] * inv, s4[3] * inv));
        *reinterpret_cast<uint2*>(Y16 + (size_t)(b * kM + m0 + m) * kC + h * kDH + dh0) = o.u2;
    }
}

// ---- output conv as bf16 MFMA GEMM: 1 wave = 16m x 64o --------------------
__global__ __launch_bounds__(64) void conv_out_gemm(const __hip_bfloat16* __restrict__ Y16,
                                                    const __hip_bfloat16* __restrict__ Wo,
                                                    float* __restrict__ out) {
    int t = threadIdx.x, li = t & 15, g = t >> 4;
    int m0 = blockIdx.x * 16, o0 = blockIdx.y * 64, b = blockIdx.z;

    bf16x8 a[8];
    const __hip_bfloat16* ap = Y16 + (size_t)(b * kM + m0 + li) * kC + g * 8;
    #pragma unroll
    for (int kb = 0; kb < 8; kb++) a[kb] = *reinterpret_cast<const bf16x8*>(ap + kb * 32);

    f32x4 acc[4] = {{0,0,0,0},{0,0,0,0},{0,0,0,0},{0,0,0,0}};
    const __hip_bfloat16* wp = Wo + g * 8;
    #pragma unroll
    for (int kb = 0; kb < 8; kb++) {
        #pragma unroll
        for (int ot = 0; ot < 4; ot++) {
            bf16x8 bw = *reinterpret_cast<const bf16x8*>(wp + (size_t)(o0 + ot * 16 + li) * kC + kb * 32);
            acc[ot] = mfma16(a[kb], bw, acc[ot]);
        }
    }
    #pragma unroll
    for (int ot = 0; ot < 4; ot++) {
        int o = o0 + ot * 16 + li;
        *reinterpret_cast<f32x4*>(out + (size_t)(b * kC + o) * kM + m0 + 4 * g) = acc[ot];
    }
}

extern "C" void kernel_launch(void* const* d_in, const int* in_sizes, int n_in,
                              void* d_out, int out_size, void* d_ws, size_t ws_size,
                              hipStream_t stream) {
    const float* x     = (const float*)d_in[0];
    const float* gamma = (const float*)d_in[1];
    const float* beta  = (const float*)d_in[2];
    const float* rmean = (const float*)d_in[3];
    const float* rvar  = (const float*)d_in[4];
    const float* v_w   = (const float*)d_in[5];
    const float* z_w   = (const float*)d_in[6];
    const float* q_w   = (const float*)d_in[7];
    const float* o_w   = (const float*)d_in[8];
    float* out = (float*)d_out;

    char* wsb = (char*)d_ws;
    const size_t BMC = (size_t)kB * kM * kC;    // 1,179,648
    float* bninv   = (float*)wsb;               // [0, 1024)
    float* bnshift = (float*)(wsb + 1024);      // [1024, 2048)
    float* PEt     = (float*)(wsb + 4096);      // [pos][c], 49152 B -> ends 53248
    __hip_bfloat16* Wv16 = (__hip_bfloat16*)(wsb + 53248);
    __hip_bfloat16* Wz16 = Wv16 + 65536;
    __hip_bfloat16* Wq16 = Wz16 + 65536;
    __hip_bfloat16* Wo16 = Wq16 + 65536;
    __hip_bfloat16* Xnt  = Wo16 + 65536;
    __hip_bfloat16* Vt   = Xnt + BMC;           // tiled (B,H,72,32,32)
    __hip_bfloat16* Zb16 = Vt + BMC;            // (B,M,C)
    __hip_bfloat16* ZRt  = Zb16 + BMC;          // tiled
    __hip_bfloat16* Qtt  = ZRt + BMC;           // tiled
    __hip_bfloat16* Y16  = Qtt + BMC;           // (B,M,C); total ~14.7 MB

    setup_kernel<<<dim3(305), dim3(256), 0, stream>>>(
        gamma, beta, rmean, rvar, v_w, z_w, q_w, o_w,
        bninv, bnshift, PEt, Wv16, Wz16, Wq16, Wo16);
    xnt_kernel<<<dim3(kM / 64, kC / 64, kB), dim3(256), 0, stream>>>(x, bninv, bnshift, Xnt);
    conv_gemm<<<dim3(kM / 16, kC / 64, 3 * kB), dim3(64), 0, stream>>>(
        Xnt, Wv16, Wz16, Wq16, Vt, Zb16, Qtt);
    zr_kernel<<<dim3(kB * kM / 4), dim3(256), 0, stream>>>(Zb16, PEt, ZRt);
    flash_attn_fused<<<dim3(kNT * kH * kB), dim3(1024), 0, stream>>>(Vt, ZRt, Qtt, Y16);
    conv_out_gemm<<<dim3(kM / 16, kC / 64, kB), dim3(64), 0, stream>>>(Y16, Wo16, out);
}

// Round 17
// 68.567 us; speedup vs baseline: 1.0682x; 1.0286x over previous
//
#include <hip/hip_runtime.h>
#include <hip/hip_bf16.h>
#include <math.h>

namespace {
constexpr int kC  = 256;   // channels
constexpr int kW  = 48;    // width
constexpr int kM  = 2304;  // tokens = 48*48
constexpr int kB  = 2;     // batch
constexpr int kDH = 32;    // head dim
constexpr int kH  = 8;     // heads
constexpr int kNT = kM / 32;  // 72 tiles of 32 tokens
}

typedef float  f32x4   __attribute__((ext_vector_type(4)));
typedef float  f32x16  __attribute__((ext_vector_type(16)));
typedef __bf16 bf16x8  __attribute__((ext_vector_type(8)));

// 16x16x32: A row=lane&15 ; B col=lane&15 ; D col=lane&15, row=(lane>>4)*4+reg
__device__ __forceinline__ f32x4 mfma16(bf16x8 a, bf16x8 b, f32x4 c) {
    return __builtin_amdgcn_mfma_f32_16x16x32_bf16(a, b, c, 0, 0, 0);
}
// 32x32x16: A row=lane&31 ; B col=lane&31 ; D col=lane&31, row=(reg&3)+8*(reg>>2)+4*(lane>>5)
__device__ __forceinline__ f32x16 mfma32(bf16x8 a, bf16x8 b, f32x16 c) {
    return __builtin_amdgcn_mfma_f32_32x32x16_bf16(a, b, c, 0, 0, 0);
}
__device__ __forceinline__ float hexp2(float x) { return __builtin_amdgcn_exp2f(x); }

// Tiled layouts: X_t[b][h][tile][row32][ch32], 1024 bf16/tile -> flash fragment
// loads are contiguous 2KB slabs (r14 win: 92->69us, L2-line scatter removed).

// ---- one-shot setup: pack 4 weights to bf16, BN scale/shift, PE table ----
__global__ __launch_bounds__(256) void setup_kernel(
    const float* __restrict__ gamma, const float* __restrict__ beta,
    const float* __restrict__ rmean, const float* __restrict__ rvar,
    const float* __restrict__ w0, const float* __restrict__ w1,
    const float* __restrict__ w2, const float* __restrict__ w3,
    float* __restrict__ bninv, float* __restrict__ bnshift, float* __restrict__ PEt,
    __hip_bfloat16* __restrict__ o0, __hip_bfloat16* __restrict__ o1,
    __hip_bfloat16* __restrict__ o2, __hip_bfloat16* __restrict__ o3) {
    int bid = blockIdx.x, t = threadIdx.x;
    if (bid < 256) {            // weight packing: weight bid>>6, chunk bid&63
        int wi = bid >> 6;
        const float* w = wi == 0 ? w0 : wi == 1 ? w1 : wi == 2 ? w2 : w3;
        __hip_bfloat16* o = wi == 0 ? o0 : wi == 1 ? o1 : wi == 2 ? o2 : o3;
        int idx = ((bid & 63) * 256 + t) * 4;
        float4 v = *reinterpret_cast<const float4*>(w + idx);
        o[idx]     = __float2bfloat16(v.x);
        o[idx + 1] = __float2bfloat16(v.y);
        o[idx + 2] = __float2bfloat16(v.z);
        o[idx + 3] = __float2bfloat16(v.w);
    } else if (bid == 256) {    // BN scale/shift
        float iv = gamma[t] / sqrtf(rvar[t] + 1e-5f);
        bninv[t] = iv;
        bnshift[t] = beta[t] - rmean[t] * iv;
    } else {                    // PE table [pos][c], pos = bid-257 (48 blocks)
        int pos = bid - 257;
        int cc = (t < 128) ? t : (t - 128);
        float dv = __expf((float)(cc & ~1) * (float)(-9.210340371976184 / 128.0));
        float pd = (float)pos * dv;
        float rv = (t & 1) ? cosf(pd) : sinf(pd);
        const float RINV = 1.0f / sqrtf(128.0f + 1e-6f);
        PEt[pos * 256 + t] = rv * RINV;
    }
}

// ---- xn^T: (B,C,M) fp32 + BN -> (B,M,C) bf16 ------------------------------
__global__ __launch_bounds__(256) void xnt_kernel(const float* __restrict__ x,
                                                  const float* __restrict__ bninv,
                                                  const float* __restrict__ bnshift,
                                                  __hip_bfloat16* __restrict__ Xnt) {
    __shared__ float T[64][65];
    int t = threadIdx.x;
    int m0 = blockIdx.x * 64, c0 = blockIdx.y * 64, b = blockIdx.z;
    int ml = t & 63;
    #pragma unroll
    for (int i = 0; i < 16; i++) {
        int c = (t >> 6) + i * 4;
        T[c][ml] = x[(size_t)(b * kC + c0 + c) * kM + m0 + ml] * bninv[c0 + c] + bnshift[c0 + c];
    }
    __syncthreads();
    int mr = t >> 2, cseg = (t & 3) * 16;
    __hip_bfloat16 v[16];
    #pragma unroll
    for (int j = 0; j < 16; j++) v[j] = __float2bfloat16(T[cseg + j][mr]);
    __hip_bfloat16* dst = Xnt + (size_t)(b * kM + m0 + mr) * kC + c0 + cseg;
    *reinterpret_cast<bf16x8*>(dst)     = *reinterpret_cast<bf16x8*>(&v[0]);
    *reinterpret_cast<bf16x8*>(dst + 8) = *reinterpret_cast<bf16x8*>(&v[8]);
}

// ---- fused-BN 1x1 convs, 3 matrices PER BLOCK (shared A-fragments) -------
// One wave = 16m x 64o; computes V, Z, Q for the same tile -> A loaded once
// instead of 3x (A-scatter-loads were the conv bottleneck candidate).
// mat V -> Vt tiled (prescaled log2e/sqrt32); Z -> Zb16 (B,M,C); Q -> Qtt tiled
__global__ __launch_bounds__(64) void conv_gemm(const __hip_bfloat16* __restrict__ Xnt,
                                                const __hip_bfloat16* __restrict__ Wv,
                                                const __hip_bfloat16* __restrict__ Wz,
                                                const __hip_bfloat16* __restrict__ Wq,
                                                __hip_bfloat16* __restrict__ Vt,
                                                __hip_bfloat16* __restrict__ Zb16,
                                                __hip_bfloat16* __restrict__ Qtt) {
    int t = threadIdx.x, li = t & 15, g = t >> 4;
    int m0 = blockIdx.x * 16, o0 = blockIdx.y * 64;
    int b = blockIdx.z;

    bf16x8 a[8];
    const __hip_bfloat16* ap = Xnt + (size_t)(b * kM + m0 + li) * kC + g * 8;
    #pragma unroll
    for (int kb = 0; kb < 8; kb++) a[kb] = *reinterpret_cast<const bf16x8*>(ap + kb * 32);

    const int mt = m0 >> 5;            // tile index
    const int mmb = m0 & 31;           // row offset within tile

    // ---- V ----
    {
        f32x4 acc[4] = {{0,0,0,0},{0,0,0,0},{0,0,0,0},{0,0,0,0}};
        const __hip_bfloat16* wp = Wv + g * 8;
        #pragma unroll
        for (int kb = 0; kb < 8; kb++)
            #pragma unroll
            for (int ot = 0; ot < 4; ot++) {
                bf16x8 bw = *reinterpret_cast<const bf16x8*>(wp + (size_t)(o0 + ot * 16 + li) * kC + kb * 32);
                acc[ot] = mfma16(a[kb], bw, acc[ot]);
            }
        const float SCALE2 = 0.25501988169885635f;   // (1/sqrt32)*log2e
        #pragma unroll
        for (int ot = 0; ot < 4; ot++) {
            int o = o0 + ot * 16 + li, hh = o >> 5, cc = o & 31;
            __hip_bfloat16* base = Vt + (((size_t)(b * kH + hh) * kNT + mt) * 32) * 32 + cc;
            #pragma unroll
            for (int r = 0; r < 4; r++)
                base[(mmb + 4 * g + r) * 32] = __float2bfloat16(acc[ot][r] * SCALE2);
        }
    }
    // ---- Z ----
    {
        f32x4 acc[4] = {{0,0,0,0},{0,0,0,0},{0,0,0,0},{0,0,0,0}};
        const __hip_bfloat16* wp = Wz + g * 8;
        #pragma unroll
        for (int kb = 0; kb < 8; kb++)
            #pragma unroll
            for (int ot = 0; ot < 4; ot++) {
                bf16x8 bw = *reinterpret_cast<const bf16x8*>(wp + (size_t)(o0 + ot * 16 + li) * kC + kb * 32);
                acc[ot] = mfma16(a[kb], bw, acc[ot]);
            }
        #pragma unroll
        for (int ot = 0; ot < 4; ot++)
            #pragma unroll
            for (int r = 0; r < 4; r++)
                Zb16[(size_t)(b * kM + m0 + 4 * g + r) * kC + o0 + ot * 16 + li] = __float2bfloat16(acc[ot][r]);
    }
    // ---- Q ----
    {
        f32x4 acc[4] = {{0,0,0,0},{0,0,0,0},{0,0,0,0},{0,0,0,0}};
        const __hip_bfloat16* wp = Wq + g * 8;
        #pragma unroll
        for (int kb = 0; kb < 8; kb++)
            #pragma unroll
            for (int ot = 0; ot < 4; ot++) {
                bf16x8 bw = *reinterpret_cast<const bf16x8*>(wp + (size_t)(o0 + ot * 16 + li) * kC + kb * 32);
                acc[ot] = mfma16(a[kb], bw, acc[ot]);
            }
        #pragma unroll
        for (int ot = 0; ot < 4; ot++) {
            int o = o0 + ot * 16 + li, hh = o >> 5, d = o & 31;
            __hip_bfloat16* base = Qtt + (((size_t)(b * kH + hh) * kNT + mt) * 32 + d) * 32 + mmb + 4 * g;
            *reinterpret_cast<__hip_bfloat162*>(base) =
                __float22bfloat162_rn(make_float2(acc[ot][0], acc[ot][1]));
            *reinterpret_cast<__hip_bfloat162*>(base + 2) =
                __float22bfloat162_rn(make_float2(acc[ot][2], acc[ot][3]));
        }
    }
}

// ---- zr = l2n(z) + l2n(r): 4 tokens/block, 1 wave/token -> ZRt tiled -----
__global__ __launch_bounds__(256) void zr_kernel(const __hip_bfloat16* __restrict__ Z,
                                                 const float* __restrict__ PEt,
                                                 __hip_bfloat16* __restrict__ ZRt) {
    int t = threadIdx.x;
    int bm = blockIdx.x * 4 + (t >> 6);   // token
    int lane = t & 63;                     // 4 channels each
    int m = bm % kM, b = bm / kM;
    union { uint2 u; __hip_bfloat16 h[4]; } zu;
    zu.u = *reinterpret_cast<const uint2*>(Z + (size_t)bm * kC + lane * 4);
    float z[4];
    #pragma unroll
    for (int j = 0; j < 4; j++) z[j] = __bfloat162float(zu.h[j]);
    float ss = (z[0]*z[0] + z[1]*z[1]) + (z[2]*z[2] + z[3]*z[3]);
    #pragma unroll
    for (int k = 32; k >= 1; k >>= 1) ss += __shfl_xor(ss, k);
    float zinv = 1.0f / sqrtf(ss + 1e-6f);
    int pos = (lane < 32) ? (m % kW) : (m / kW);
    f32x4 pe = *reinterpret_cast<const f32x4*>(PEt + pos * 256 + lane * 4);
    union { uint2 u; __hip_bfloat16 h[4]; } ou;
    #pragma unroll
    for (int j = 0; j < 4; j++) ou.h[j] = __float2bfloat16(z[j] * zinv + pe[j]);
    int hh = lane >> 3, cc = (lane * 4) & 31;
    *reinterpret_cast<uint2*>(
        ZRt + (((size_t)(b * kH + hh) * kNT + (m >> 5)) * 32 + (m & 31)) * 32 + cc) = ou.u;
}

// ---- fused flash attention on tiled layouts (r14-exact, best known) ------
// Flat 1152-block grid, XCD decode: bh = blk & 15, mtile = blk >> 4.
// 8 waves/block; wave w owns KV tiles [w*9, w*9+9). 1-deep register prefetch.
// PV B-frag via cvt_pk + v_permlane32_swap (vdst.hi <-> vsrc.lo, r10/r11).
// No max-tracking (|logit*log2e| <~ 33; exp2 fp32-safe). Epilogue LDS combine.
__global__ __launch_bounds__(512) void flash_attn_fused(
    const __hip_bfloat16* __restrict__ Vt,   // (B,H,72,32m,32c) prescaled
    const __hip_bfloat16* __restrict__ ZRt,  // (B,H,72,32n,32c)
    const __hip_bfloat16* __restrict__ Qtt,  // (B,H,72,32d,32n)
    __hip_bfloat16* __restrict__ Y16)        // (B,M,C)
{
    __shared__ float Aw[8][32 * 36];   // per-wave Y^T partial, [m][dh] pitch 36
    __shared__ float Ls[8][64];        // per-wave per-lane lsum partials
    const int t = threadIdx.x;
    const int w = t >> 6, lane = t & 63;
    const int c = lane & 31, hi = lane >> 5;
    const int blk = blockIdx.x;
    const int bh = blk & 15, mtile = blk >> 4;
    const int b = bh >> 3, h = bh & 7;
    const int m0 = mtile * 32;
    const f32x16 zero16 = {0,0,0,0,0,0,0,0,0,0,0,0,0,0,0,0};

    const int lo = c * 32 + hi * 8;    // lane offset within a 1024-elem tile
    const size_t hb = (size_t)bh * kNT;

    const __hip_bfloat16* vb = Vt + (hb + mtile) * 1024 + lo;
    bf16x8 vf0 = *reinterpret_cast<const bf16x8*>(vb);
    bf16x8 vf1 = *reinterpret_cast<const bf16x8*>(vb + 16);

    const __hip_bfloat16* zb = ZRt + (hb + w * 9) * 1024 + lo;   // walk +1024/iter
    const __hip_bfloat16* qb = Qtt + (hb + w * 9) * 1024 + lo;

    f32x16 acc = zero16;
    float lsum = 0.f;

    bf16x8 za0 = *reinterpret_cast<const bf16x8*>(zb);
    bf16x8 za1 = *reinterpret_cast<const bf16x8*>(zb + 16);
    bf16x8 qa0 = *reinterpret_cast<const bf16x8*>(qb);
    bf16x8 qa1 = *reinterpret_cast<const bf16x8*>(qb + 16);

    for (int it = 0; it < 9; ++it) {
        const int nx = (it < 8) ? (it + 1) * 1024 : 0;   // harmless wrap

        // QK^T
        f32x16 st = mfma32(za0, vf0, zero16);
        st = mfma32(za1, vf1, st);

        // prefetch next tile's fragments (contiguous 2KB slabs)
        bf16x8 za0n = *reinterpret_cast<const bf16x8*>(zb + nx);
        bf16x8 za1n = *reinterpret_cast<const bf16x8*>(zb + nx + 16);
        bf16x8 qa0n = *reinterpret_cast<const bf16x8*>(qb + nx);
        bf16x8 qa1n = *reinterpret_cast<const bf16x8*>(qb + nx + 16);

        // raw exp2 (no max subtraction), tree sum
        float p[16];
        #pragma unroll
        for (int r = 0; r < 16; r++) p[r] = hexp2(st[r]);
        float s01 = (p[0] + p[1]) + (p[2] + p[3]);
        float s23 = (p[4] + p[5]) + (p[6] + p[7]);
        float s45 = (p[8] + p[9]) + (p[10] + p[11]);
        float s67 = (p[12] + p[13]) + (p[14] + p[15]);
        lsum += (s01 + s23) + (s45 + s67);

        // PV: two K=16 MFMAs; B-frags via cvt_pk + permlane32_swap
        #pragma unroll
        for (int kk = 0; kk < 2; kk++) {
            __hip_bfloat162 xw0 = __float22bfloat162_rn(make_float2(p[8*kk+0], p[8*kk+1]));
            __hip_bfloat162 xw1 = __float22bfloat162_rn(make_float2(p[8*kk+2], p[8*kk+3]));
            __hip_bfloat162 yw0 = __float22bfloat162_rn(make_float2(p[8*kk+4], p[8*kk+5]));
            __hip_bfloat162 yw1 = __float22bfloat162_rn(make_float2(p[8*kk+6], p[8*kk+7]));
            unsigned x0 = *reinterpret_cast<unsigned*>(&xw0);
            unsigned x1 = *reinterpret_cast<unsigned*>(&xw1);
            unsigned y0 = *reinterpret_cast<unsigned*>(&yw0);
            unsigned y1 = *reinterpret_cast<unsigned*>(&yw1);
            // vdst.hi <-> vsrc.lo: hi=0: {own x, partner x}; hi=1: {partner y, own y}
            asm("v_permlane32_swap_b32 %0, %1" : "+v"(x0), "+v"(y0));
            asm("v_permlane32_swap_b32 %0, %1" : "+v"(x1), "+v"(y1));
            union { unsigned u[4]; bf16x8 v; } bf;
            bf.u[0] = x0; bf.u[1] = x1; bf.u[2] = y0; bf.u[3] = y1;
            acc = mfma32(kk == 0 ? qa0 : qa1, bf.v, acc);
        }

        za0 = za0n; za1 = za1n; qa0 = qa0n; qa1 = qa1n;
    }

    // epilogue: stage partials, combine across the 8 waves
    #pragma unroll
    for (int r = 0; r < 16; r++) {
        int dh = (r & 3) + 8 * (r >> 2) + 4 * hi;
        Aw[w][c * 36 + dh] = acc[r];
    }
    Ls[w][lane] = lsum;
    __syncthreads();

    if (t < 256) {   // 32 m-rows x 8 dh-groups of 4
        const int m = t & 31, dh0 = (t >> 5) * 4;
        float L = 0.f;
        #pragma unroll
        for (int w2 = 0; w2 < 8; w2++) L += Ls[w2][m] + Ls[w2][m + 32];
        f32x4 s4 = {0.f, 0.f, 0.f, 0.f};
        #pragma unroll
        for (int w2 = 0; w2 < 8; w2++)
            s4 = s4 + *reinterpret_cast<const f32x4*>(&Aw[w2][m * 36 + dh0]);
        float inv = 1.0f / L;
        union { uint2 u2; __hip_bfloat162 h2[2]; } o;
        o.h2[0] = __float22bfloat162_rn(make_float2(s4[0] * inv, s4[1] * inv));
        o.h2[1] = __float22bfloat162_rn(make_float2(s4[2] * inv, s4[3] * inv));
        *reinterpret_cast<uint2*>(Y16 + (size_t)(b * kM + m0 + m) * kC + h * kDH + dh0) = o.u2;
    }
}

// ---- output conv as bf16 MFMA GEMM: 1 wave = 16m x 64o --------------------
__global__ __launch_bounds__(64) void conv_out_gemm(const __hip_bfloat16* __restrict__ Y16,
                                                    const __hip_bfloat16* __restrict__ Wo,
                                                    float* __restrict__ out) {
    int t = threadIdx.x, li = t & 15, g = t >> 4;
    int m0 = blockIdx.x * 16, o0 = blockIdx.y * 64, b = blockIdx.z;

    bf16x8 a[8];
    const __hip_bfloat16* ap = Y16 + (size_t)(b * kM + m0 + li) * kC + g * 8;
    #pragma unroll
    for (int kb = 0; kb < 8; kb++) a[kb] = *reinterpret_cast<const bf16x8*>(ap + kb * 32);

    f32x4 acc[4] = {{0,0,0,0},{0,0,0,0},{0,0,0,0},{0,0,0,0}};
    const __hip_bfloat16* wp = Wo + g * 8;
    #pragma unroll
    for (int kb = 0; kb < 8; kb++) {
        #pragma unroll
        for (int ot = 0; ot < 4; ot++) {
            bf16x8 bw = *reinterpret_cast<const bf16x8*>(wp + (size_t)(o0 + ot * 16 + li) * kC + kb * 32);
            acc[ot] = mfma16(a[kb], bw, acc[ot]);
        }
    }
    #pragma unroll
    for (int ot = 0; ot < 4; ot++) {
        int o = o0 + ot * 16 + li;
        *reinterpret_cast<f32x4*>(out + (size_t)(b * kC + o) * kM + m0 + 4 * g) = acc[ot];
    }
}

extern "C" void kernel_launch(void* const* d_in, const int* in_sizes, int n_in,
                              void* d_out, int out_size, void* d_ws, size_t ws_size,
                              hipStream_t stream) {
    const float* x     = (const float*)d_in[0];
    const float* gamma = (const float*)d_in[1];
    const float* beta  = (const float*)d_in[2];
    const float* rmean = (const float*)d_in[3];
    const float* rvar  = (const float*)d_in[4];
    const float* v_w   = (const float*)d_in[5];
    const float* z_w   = (const float*)d_in[6];
    const float* q_w   = (const float*)d_in[7];
    const float* o_w   = (const float*)d_in[8];
    float* out = (float*)d_out;

    char* wsb = (char*)d_ws;
    const size_t BMC = (size_t)kB * kM * kC;    // 1,179,648
    float* bninv   = (float*)wsb;               // [0, 1024)
    float* bnshift = (float*)(wsb + 1024);      // [1024, 2048)
    float* PEt     = (float*)(wsb + 4096);      // [pos][c], 49152 B -> ends 53248
    __hip_bfloat16* Wv16 = (__hip_bfloat16*)(wsb + 53248);
    __hip_bfloat16* Wz16 = Wv16 + 65536;
    __hip_bfloat16* Wq16 = Wz16 + 65536;
    __hip_bfloat16* Wo16 = Wq16 + 65536;
    __hip_bfloat16* Xnt  = Wo16 + 65536;
    __hip_bfloat16* Vt   = Xnt + BMC;           // tiled (B,H,72,32,32)
    __hip_bfloat16* Zb16 = Vt + BMC;            // (B,M,C)
    __hip_bfloat16* ZRt  = Zb16 + BMC;          // tiled
    __hip_bfloat16* Qtt  = ZRt + BMC;           // tiled
    __hip_bfloat16* Y16  = Qtt + BMC;           // (B,M,C); total ~14.7 MB

    setup_kernel<<<dim3(305), dim3(256), 0, stream>>>(
        gamma, beta, rmean, rvar, v_w, z_w, q_w, o_w,
        bninv, bnshift, PEt, Wv16, Wz16, Wq16, Wo16);
    xnt_kernel<<<dim3(kM / 64, kC / 64, kB), dim3(256), 0, stream>>>(x, bninv, bnshift, Xnt);
    conv_gemm<<<dim3(kM / 16, kC / 64, kB), dim3(64), 0, stream>>>(
        Xnt, Wv16, Wz16, Wq16, Vt, Zb16, Qtt);
    zr_kernel<<<dim3(kB * kM / 4), dim3(256), 0, stream>>>(Zb16, PEt, ZRt);
    flash_attn_fused<<<dim3(kNT * kH * kB), dim3(512), 0, stream>>>(Vt, ZRt, Qtt, Y16);
    conv_out_gemm<<<dim3(kM / 16, kC / 64, kB), dim3(64), 0, stream>>>(Y16, Wo16, out);
}

// Round 18
// 67.419 us; speedup vs baseline: 1.0864x; 1.0170x over previous
//
#include <hip/hip_runtime.h>
#include <hip/hip_bf16.h>
#include <math.h>

namespace {
constexpr int kC  = 256;   // channels
constexpr int kW  = 48;    // width
constexpr int kM  = 2304;  // tokens = 48*48
constexpr int kB  = 2;     // batch
constexpr int kDH = 32;    // head dim
constexpr int kH  = 8;     // heads
constexpr int kNT = kM / 32;  // 72 tiles of 32 tokens
}

typedef float  f32x4   __attribute__((ext_vector_type(4)));
typedef float  f32x16  __attribute__((ext_vector_type(16)));
typedef __bf16 bf16x8  __attribute__((ext_vector_type(8)));

// 16x16x32: A row=lane&15 ; B col=lane&15 ; D col=lane&15, row=(lane>>4)*4+reg
__device__ __forceinline__ f32x4 mfma16(bf16x8 a, bf16x8 b, f32x4 c) {
    return __builtin_amdgcn_mfma_f32_16x16x32_bf16(a, b, c, 0, 0, 0);
}
// 32x32x16: A row=lane&31 ; B col=lane&31 ; D col=lane&31, row=(reg&3)+8*(reg>>2)+4*(lane>>5)
__device__ __forceinline__ f32x16 mfma32(bf16x8 a, bf16x8 b, f32x16 c) {
    return __builtin_amdgcn_mfma_f32_32x32x16_bf16(a, b, c, 0, 0, 0);
}
__device__ __forceinline__ float hexp2(float x) { return __builtin_amdgcn_exp2f(x); }

// Tiled layouts: X_t[b][h][tile][row32][ch32], 1024 bf16/tile -> flash fragment
// loads are contiguous 2KB slabs (r14 win: 92->69us, L2-line scatter removed).

// ---- one-shot setup: pack 4 weights to bf16, BN scale/shift, PE table ----
__global__ __launch_bounds__(256) void setup_kernel(
    const float* __restrict__ gamma, const float* __restrict__ beta,
    const float* __restrict__ rmean, const float* __restrict__ rvar,
    const float* __restrict__ w0, const float* __restrict__ w1,
    const float* __restrict__ w2, const float* __restrict__ w3,
    float* __restrict__ bninv, float* __restrict__ bnshift, float* __restrict__ PEt,
    __hip_bfloat16* __restrict__ o0, __hip_bfloat16* __restrict__ o1,
    __hip_bfloat16* __restrict__ o2, __hip_bfloat16* __restrict__ o3) {
    int bid = blockIdx.x, t = threadIdx.x;
    if (bid < 256) {            // weight packing: weight bid>>6, chunk bid&63
        int wi = bid >> 6;
        const float* w = wi == 0 ? w0 : wi == 1 ? w1 : wi == 2 ? w2 : w3;
        __hip_bfloat16* o = wi == 0 ? o0 : wi == 1 ? o1 : wi == 2 ? o2 : o3;
        int idx = ((bid & 63) * 256 + t) * 4;
        float4 v = *reinterpret_cast<const float4*>(w + idx);
        o[idx]     = __float2bfloat16(v.x);
        o[idx + 1] = __float2bfloat16(v.y);
        o[idx + 2] = __float2bfloat16(v.z);
        o[idx + 3] = __float2bfloat16(v.w);
    } else if (bid == 256) {    // BN scale/shift
        float iv = gamma[t] / sqrtf(rvar[t] + 1e-5f);
        bninv[t] = iv;
        bnshift[t] = beta[t] - rmean[t] * iv;
    } else {                    // PE table [pos][c], pos = bid-257 (48 blocks)
        int pos = bid - 257;
        int cc = (t < 128) ? t : (t - 128);
        float dv = __expf((float)(cc & ~1) * (float)(-9.210340371976184 / 128.0));
        float pd = (float)pos * dv;
        float rv = (t & 1) ? cosf(pd) : sinf(pd);
        const float RINV = 1.0f / sqrtf(128.0f + 1e-6f);
        PEt[pos * 256 + t] = rv * RINV;
    }
}

// ---- xn^T: (B,C,M) fp32 + BN -> (B,M,C) bf16 ------------------------------
__global__ __launch_bounds__(256) void xnt_kernel(const float* __restrict__ x,
                                                  const float* __restrict__ bninv,
                                                  const float* __restrict__ bnshift,
                                                  __hip_bfloat16* __restrict__ Xnt) {
    __shared__ float T[64][65];
    int t = threadIdx.x;
    int m0 = blockIdx.x * 64, c0 = blockIdx.y * 64, b = blockIdx.z;
    int ml = t & 63;
    #pragma unroll
    for (int i = 0; i < 16; i++) {
        int c = (t >> 6) + i * 4;
        T[c][ml] = x[(size_t)(b * kC + c0 + c) * kM + m0 + ml] * bninv[c0 + c] + bnshift[c0 + c];
    }
    __syncthreads();
    int mr = t >> 2, cseg = (t & 3) * 16;
    __hip_bfloat16 v[16];
    #pragma unroll
    for (int j = 0; j < 16; j++) v[j] = __float2bfloat16(T[cseg + j][mr]);
    __hip_bfloat16* dst = Xnt + (size_t)(b * kM + m0 + mr) * kC + c0 + cseg;
    *reinterpret_cast<bf16x8*>(dst)     = *reinterpret_cast<bf16x8*>(&v[0]);
    *reinterpret_cast<bf16x8*>(dst + 8) = *reinterpret_cast<bf16x8*>(&v[8]);
}

// ---- fused-BN 1x1 convs, 3 matrices PER BLOCK (shared A-fragments) -------
__global__ __launch_bounds__(64) void conv_gemm(const __hip_bfloat16* __restrict__ Xnt,
                                                const __hip_bfloat16* __restrict__ Wv,
                                                const __hip_bfloat16* __restrict__ Wz,
                                                const __hip_bfloat16* __restrict__ Wq,
                                                __hip_bfloat16* __restrict__ Vt,
                                                __hip_bfloat16* __restrict__ Zb16,
                                                __hip_bfloat16* __restrict__ Qtt) {
    int t = threadIdx.x, li = t & 15, g = t >> 4;
    int m0 = blockIdx.x * 16, o0 = blockIdx.y * 64;
    int b = blockIdx.z;

    bf16x8 a[8];
    const __hip_bfloat16* ap = Xnt + (size_t)(b * kM + m0 + li) * kC + g * 8;
    #pragma unroll
    for (int kb = 0; kb < 8; kb++) a[kb] = *reinterpret_cast<const bf16x8*>(ap + kb * 32);

    const int mt = m0 >> 5;            // tile index
    const int mmb = m0 & 31;           // row offset within tile

    // ---- V ----
    {
        f32x4 acc[4] = {{0,0,0,0},{0,0,0,0},{0,0,0,0},{0,0,0,0}};
        const __hip_bfloat16* wp = Wv + g * 8;
        #pragma unroll
        for (int kb = 0; kb < 8; kb++)
            #pragma unroll
            for (int ot = 0; ot < 4; ot++) {
                bf16x8 bw = *reinterpret_cast<const bf16x8*>(wp + (size_t)(o0 + ot * 16 + li) * kC + kb * 32);
                acc[ot] = mfma16(a[kb], bw, acc[ot]);
            }
        const float SCALE2 = 0.25501988169885635f;   // (1/sqrt32)*log2e
        #pragma unroll
        for (int ot = 0; ot < 4; ot++) {
            int o = o0 + ot * 16 + li, hh = o >> 5, cc = o & 31;
            __hip_bfloat16* base = Vt + (((size_t)(b * kH + hh) * kNT + mt) * 32) * 32 + cc;
            #pragma unroll
            for (int r = 0; r < 4; r++)
                base[(mmb + 4 * g + r) * 32] = __float2bfloat16(acc[ot][r] * SCALE2);
        }
    }
    // ---- Z ----
    {
        f32x4 acc[4] = {{0,0,0,0},{0,0,0,0},{0,0,0,0},{0,0,0,0}};
        const __hip_bfloat16* wp = Wz + g * 8;
        #pragma unroll
        for (int kb = 0; kb < 8; kb++)
            #pragma unroll
            for (int ot = 0; ot < 4; ot++) {
                bf16x8 bw = *reinterpret_cast<const bf16x8*>(wp + (size_t)(o0 + ot * 16 + li) * kC + kb * 32);
                acc[ot] = mfma16(a[kb], bw, acc[ot]);
            }
        #pragma unroll
        for (int ot = 0; ot < 4; ot++)
            #pragma unroll
            for (int r = 0; r < 4; r++)
                Zb16[(size_t)(b * kM + m0 + 4 * g + r) * kC + o0 + ot * 16 + li] = __float2bfloat16(acc[ot][r]);
    }
    // ---- Q ----
    {
        f32x4 acc[4] = {{0,0,0,0},{0,0,0,0},{0,0,0,0},{0,0,0,0}};
        const __hip_bfloat16* wp = Wq + g * 8;
        #pragma unroll
        for (int kb = 0; kb < 8; kb++)
            #pragma unroll
            for (int ot = 0; ot < 4; ot++) {
                bf16x8 bw = *reinterpret_cast<const bf16x8*>(wp + (size_t)(o0 + ot * 16 + li) * kC + kb * 32);
                acc[ot] = mfma16(a[kb], bw, acc[ot]);
            }
        #pragma unroll
        for (int ot = 0; ot < 4; ot++) {
            int o = o0 + ot * 16 + li, hh = o >> 5, d = o & 31;
            __hip_bfloat16* base = Qtt + (((size_t)(b * kH + hh) * kNT + mt) * 32 + d) * 32 + mmb + 4 * g;
            *reinterpret_cast<__hip_bfloat162*>(base) =
                __float22bfloat162_rn(make_float2(acc[ot][0], acc[ot][1]));
            *reinterpret_cast<__hip_bfloat162*>(base + 2) =
                __float22bfloat162_rn(make_float2(acc[ot][2], acc[ot][3]));
        }
    }
}

// ---- zr = l2n(z) + l2n(r): 4 tokens/block, 1 wave/token -> ZRt tiled -----
__global__ __launch_bounds__(256) void zr_kernel(const __hip_bfloat16* __restrict__ Z,
                                                 const float* __restrict__ PEt,
                                                 __hip_bfloat16* __restrict__ ZRt) {
    int t = threadIdx.x;
    int bm = blockIdx.x * 4 + (t >> 6);   // token
    int lane = t & 63;                     // 4 channels each
    int m = bm % kM, b = bm / kM;
    union { uint2 u; __hip_bfloat16 h[4]; } zu;
    zu.u = *reinterpret_cast<const uint2*>(Z + (size_t)bm * kC + lane * 4);
    float z[4];
    #pragma unroll
    for (int j = 0; j < 4; j++) z[j] = __bfloat162float(zu.h[j]);
    float ss = (z[0]*z[0] + z[1]*z[1]) + (z[2]*z[2] + z[3]*z[3]);
    #pragma unroll
    for (int k = 32; k >= 1; k >>= 1) ss += __shfl_xor(ss, k);
    float zinv = 1.0f / sqrtf(ss + 1e-6f);
    int pos = (lane < 32) ? (m % kW) : (m / kW);
    f32x4 pe = *reinterpret_cast<const f32x4*>(PEt + pos * 256 + lane * 4);
    union { uint2 u; __hip_bfloat16 h[4]; } ou;
    #pragma unroll
    for (int j = 0; j < 4; j++) ou.h[j] = __float2bfloat16(z[j] * zinv + pe[j]);
    int hh = lane >> 3, cc = (lane * 4) & 31;
    *reinterpret_cast<uint2*>(
        ZRt + (((size_t)(b * kH + hh) * kNT + (m >> 5)) * 32 + (m & 31)) * 32 + cc) = ou.u;
}

// ---- fused flash attention, q-tile-PAIR per block (KV L2 traffic / 2) ----
// Grid 576: bh = blk & 15 (XCD-local per bh since blk = bh mod 16), pair = blk>>4.
// Block covers m-tiles {2*pair, 2*pair+1}; 8 waves each own 9 KV tiles and
// compute BOTH q-tiles from one za/qa load -> each (b,h) KV slice read by 36
// blocks instead of 72 (340MB -> 170MB L2 reads, the r17 flash limiter).
// PV B-frag via cvt_pk + v_permlane32_swap (vdst.hi <-> vsrc.lo, r10/r11).
// No max-tracking (|logit*log2e| <~ 33; exp2 fp32-safe). Epilogue LDS combine x2.
__global__ __launch_bounds__(512) void flash_attn_fused(
    const __hip_bfloat16* __restrict__ Vt,   // (B,H,72,32m,32c) prescaled
    const __hip_bfloat16* __restrict__ ZRt,  // (B,H,72,32n,32c)
    const __hip_bfloat16* __restrict__ Qtt,  // (B,H,72,32d,32n)
    __hip_bfloat16* __restrict__ Y16)        // (B,M,C)
{
    __shared__ float Aw[8][32 * 36];   // per-wave Y^T partial, [m][dh] pitch 36
    __shared__ float Ls[8][64];        // per-wave per-lane lsum partials
    const int t = threadIdx.x;
    const int w = t >> 6, lane = t & 63;
    const int c = lane & 31, hi = lane >> 5;
    const int blk = blockIdx.x;
    const int bh = blk & 15, pair = blk >> 4;
    const int b = bh >> 3, h = bh & 7;
    const f32x16 zero16 = {0,0,0,0,0,0,0,0,0,0,0,0,0,0,0,0};

    const int lo = c * 32 + hi * 8;    // lane offset within a 1024-elem tile
    const size_t hb = (size_t)bh * kNT;

    // V fragments for both q-tiles of the pair
    bf16x8 vf[2][2];
    #pragma unroll
    for (int mt = 0; mt < 2; mt++) {
        const __hip_bfloat16* vb = Vt + (hb + pair * 2 + mt) * 1024 + lo;
        vf[mt][0] = *reinterpret_cast<const bf16x8*>(vb);
        vf[mt][1] = *reinterpret_cast<const bf16x8*>(vb + 16);
    }

    const __hip_bfloat16* zb = ZRt + (hb + w * 9) * 1024 + lo;   // walk +1024/iter
    const __hip_bfloat16* qb = Qtt + (hb + w * 9) * 1024 + lo;

    f32x16 acc[2] = {zero16, zero16};
    float lsum[2] = {0.f, 0.f};

    bf16x8 za0 = *reinterpret_cast<const bf16x8*>(zb);
    bf16x8 za1 = *reinterpret_cast<const bf16x8*>(zb + 16);
    bf16x8 qa0 = *reinterpret_cast<const bf16x8*>(qb);
    bf16x8 qa1 = *reinterpret_cast<const bf16x8*>(qb + 16);

    for (int it = 0; it < 9; ++it) {
        const int nx = (it < 8) ? (it + 1) * 1024 : 0;   // harmless wrap

        // prefetch next tile's fragments (contiguous 2KB slabs)
        bf16x8 za0n = *reinterpret_cast<const bf16x8*>(zb + nx);
        bf16x8 za1n = *reinterpret_cast<const bf16x8*>(zb + nx + 16);
        bf16x8 qa0n = *reinterpret_cast<const bf16x8*>(qb + nx);
        bf16x8 qa1n = *reinterpret_cast<const bf16x8*>(qb + nx + 16);

        #pragma unroll
        for (int mt = 0; mt < 2; mt++) {
            // QK^T for q-tile mt (KV regs shared across mt)
            f32x16 st = mfma32(za0, vf[mt][0], zero16);
            st = mfma32(za1, vf[mt][1], st);

            // raw exp2 (no max subtraction), tree sum
            float p[16];
            #pragma unroll
            for (int r = 0; r < 16; r++) p[r] = hexp2(st[r]);
            float s01 = (p[0] + p[1]) + (p[2] + p[3]);
            float s23 = (p[4] + p[5]) + (p[6] + p[7]);
            float s45 = (p[8] + p[9]) + (p[10] + p[11]);
            float s67 = (p[12] + p[13]) + (p[14] + p[15]);
            lsum[mt] += (s01 + s23) + (s45 + s67);

            // PV: two K=16 MFMAs; B-frags via cvt_pk + permlane32_swap
            #pragma unroll
            for (int kk = 0; kk < 2; kk++) {
                __hip_bfloat162 xw0 = __float22bfloat162_rn(make_float2(p[8*kk+0], p[8*kk+1]));
                __hip_bfloat162 xw1 = __float22bfloat162_rn(make_float2(p[8*kk+2], p[8*kk+3]));
                __hip_bfloat162 yw0 = __float22bfloat162_rn(make_float2(p[8*kk+4], p[8*kk+5]));
                __hip_bfloat162 yw1 = __float22bfloat162_rn(make_float2(p[8*kk+6], p[8*kk+7]));
                unsigned x0 = *reinterpret_cast<unsigned*>(&xw0);
                unsigned x1 = *reinterpret_cast<unsigned*>(&xw1);
                unsigned y0 = *reinterpret_cast<unsigned*>(&yw0);
                unsigned y1 = *reinterpret_cast<unsigned*>(&yw1);
                // vdst.hi <-> vsrc.lo: hi=0: {own x, partner x}; hi=1: {partner y, own y}
                asm("v_permlane32_swap_b32 %0, %1" : "+v"(x0), "+v"(y0));
                asm("v_permlane32_swap_b32 %0, %1" : "+v"(x1), "+v"(y1));
                union { unsigned u[4]; bf16x8 v; } bf;
                bf.u[0] = x0; bf.u[1] = x1; bf.u[2] = y0; bf.u[3] = y1;
                acc[mt] = mfma32(kk == 0 ? qa0 : qa1, bf.v, acc[mt]);
            }
        }

        za0 = za0n; za1 = za1n; qa0 = qa0n; qa1 = qa1n;
    }

    // epilogue: for each q-tile, stage partials + combine across the 8 waves
    #pragma unroll
    for (int mt = 0; mt < 2; mt++) {
        #pragma unroll
        for (int r = 0; r < 16; r++) {
            int dh = (r & 3) + 8 * (r >> 2) + 4 * hi;
            Aw[w][c * 36 + dh] = acc[mt][r];
        }
        Ls[w][lane] = lsum[mt];
        __syncthreads();

        if (t < 256) {   // 32 m-rows x 8 dh-groups of 4
            const int m = t & 31, dh0 = (t >> 5) * 4;
            float L = 0.f;
            #pragma unroll
            for (int w2 = 0; w2 < 8; w2++) L += Ls[w2][m] + Ls[w2][m + 32];
            f32x4 s4 = {0.f, 0.f, 0.f, 0.f};
            #pragma unroll
            for (int w2 = 0; w2 < 8; w2++)
                s4 = s4 + *reinterpret_cast<const f32x4*>(&Aw[w2][m * 36 + dh0]);
            float inv = 1.0f / L;
            union { uint2 u2; __hip_bfloat162 h2[2]; } o;
            o.h2[0] = __float22bfloat162_rn(make_float2(s4[0] * inv, s4[1] * inv));
            o.h2[1] = __float22bfloat162_rn(make_float2(s4[2] * inv, s4[3] * inv));
            *reinterpret_cast<uint2*>(
                Y16 + (size_t)(b * kM + (pair * 2 + mt) * 32 + m) * kC + h * kDH + dh0) = o.u2;
        }
        __syncthreads();   // WAR: next mt's staging must not race this combine
    }
}

// ---- output conv as bf16 MFMA GEMM: 1 wave = 16m x 64o --------------------
__global__ __launch_bounds__(64) void conv_out_gemm(const __hip_bfloat16* __restrict__ Y16,
                                                    const __hip_bfloat16* __restrict__ Wo,
                                                    float* __restrict__ out) {
    int t = threadIdx.x, li = t & 15, g = t >> 4;
    int m0 = blockIdx.x * 16, o0 = blockIdx.y * 64, b = blockIdx.z;

    bf16x8 a[8];
    const __hip_bfloat16* ap = Y16 + (size_t)(b * kM + m0 + li) * kC + g * 8;
    #pragma unroll
    for (int kb = 0; kb < 8; kb++) a[kb] = *reinterpret_cast<const bf16x8*>(ap + kb * 32);

    f32x4 acc[4] = {{0,0,0,0},{0,0,0,0},{0,0,0,0},{0,0,0,0}};
    const __hip_bfloat16* wp = Wo + g * 8;
    #pragma unroll
    for (int kb = 0; kb < 8; kb++) {
        #pragma unroll
        for (int ot = 0; ot < 4; ot++) {
            bf16x8 bw = *reinterpret_cast<const bf16x8*>(wp + (size_t)(o0 + ot * 16 + li) * kC + kb * 32);
            acc[ot] = mfma16(a[kb], bw, acc[ot]);
        }
    }
    #pragma unroll
    for (int ot = 0; ot < 4; ot++) {
        int o = o0 + ot * 16 + li;
        *reinterpret_cast<f32x4*>(out + (size_t)(b * kC + o) * kM + m0 + 4 * g) = acc[ot];
    }
}

extern "C" void kernel_launch(void* const* d_in, const int* in_sizes, int n_in,
                              void* d_out, int out_size, void* d_ws, size_t ws_size,
                              hipStream_t stream) {
    const float* x     = (const float*)d_in[0];
    const float* gamma = (const float*)d_in[1];
    const float* beta  = (const float*)d_in[2];
    const float* rmean = (const float*)d_in[3];
    const float* rvar  = (const float*)d_in[4];
    const float* v_w   = (const float*)d_in[5];
    const float* z_w   = (const float*)d_in[6];
    const float* q_w   = (const float*)d_in[7];
    const float* o_w   = (const float*)d_in[8];
    float* out = (float*)d_out;

    char* wsb = (char*)d_ws;
    const size_t BMC = (size_t)kB * kM * kC;    // 1,179,648
    float* bninv   = (float*)wsb;               // [0, 1024)
    float* bnshift = (float*)(wsb + 1024);      // [1024, 2048)
    float* PEt     = (float*)(wsb + 4096);      // [pos][c], 49152 B -> ends 53248
    __hip_bfloat16* Wv16 = (__hip_bfloat16*)(wsb + 53248);
    __hip_bfloat16* Wz16 = Wv16 + 65536;
    __hip_bfloat16* Wq16 = Wz16 + 65536;
    __hip_bfloat16* Wo16 = Wq16 + 65536;
    __hip_bfloat16* Xnt  = Wo16 + 65536;
    __hip_bfloat16* Vt   = Xnt + BMC;           // tiled (B,H,72,32,32)
    __hip_bfloat16* Zb16 = Vt + BMC;            // (B,M,C)
    __hip_bfloat16* ZRt  = Zb16 + BMC;          // tiled
    __hip_bfloat16* Qtt  = ZRt + BMC;           // tiled
    __hip_bfloat16* Y16  = Qtt + BMC;           // (B,M,C); total ~14.7 MB

    setup_kernel<<<dim3(305), dim3(256), 0, stream>>>(
        gamma, beta, rmean, rvar, v_w, z_w, q_w, o_w,
        bninv, bnshift, PEt, Wv16, Wz16, Wq16, Wo16);
    xnt_kernel<<<dim3(kM / 64, kC / 64, kB), dim3(256), 0, stream>>>(x, bninv, bnshift, Xnt);
    conv_gemm<<<dim3(kM / 16, kC / 64, kB), dim3(64), 0, stream>>>(
        Xnt, Wv16, Wz16, Wq16, Vt, Zb16, Qtt);
    zr_kernel<<<dim3(kB * kM / 4), dim3(256), 0, stream>>>(Zb16, PEt, ZRt);
    flash_attn_fused<<<dim3((kNT / 2) * kH * kB), dim3(512), 0, stream>>>(Vt, ZRt, Qtt, Y16);
    conv_out_gemm<<<dim3(kM / 16, kC / 64, kB), dim3(64), 0, stream>>>(Y16, Wo16, out);
}